// Round 13
// baseline (429.737 us; speedup 1.0000x reference)
//
#include <hip/hip_runtime.h>
#include <hip/hip_fp16.h>
#include <stdint.h>

// GCN 2-layer forward: two-level counting sort -> dst-sorted CSR (segments
// partitioned by src-half) -> TWO gather passes, each touching only 3.2MB of
// the int8 h1q array (fits per-XCD 4MB L2 -> random reads become hits).
// h1q: per-row-scaled int8 + fp32 scale table. GEMM via MFMA.

#define TPB 256
#define TILE 512           // nodes per bucket
#define TSH  9
#define MAXB 512           // supports N <= 262144 (src must fit 18 bits)

typedef _Float16 f16x8 __attribute__((ext_vector_type(8)));
typedef float    f32x4 __attribute__((ext_vector_type(4)));

__global__ void k_zero_i(int* __restrict__ p, int m) {
    int i = blockIdx.x * TPB + threadIdx.x;
    if (i < m) p[i] = 0;
}

// chunked per-bucket histogram; spills per-block counts to hall and sums bcnt.
__global__ __launch_bounds__(1024) void k_bhist(const int* __restrict__ dst,
                                                int* __restrict__ bcnt,
                                                int* __restrict__ hall,
                                                int e, int chunk, int nb) {
    __shared__ int h[MAXB];
    int t = threadIdx.x, b = blockIdx.x;
    for (int i = t; i < MAXB; i += 1024) h[i] = 0;
    __syncthreads();
    int e0 = b * chunk, e1 = min(e0 + chunk, e);
    for (int i = e0 + t; i < e1; i += 1024)
        atomicAdd(&h[dst[i] >> TSH], 1);
    __syncthreads();
    for (int i = t; i < nb; i += 1024) {
        int c = h[i];
        hall[(size_t)b * MAXB + i] = c;
        if (c) atomicAdd(&bcnt[i], c);
    }
}

// single-block exclusive scan of bucket counts -> bstart, init bcursor
__global__ void k_bscan(const int* __restrict__ bcnt, int* __restrict__ bstart,
                        int* __restrict__ bcursor, int nb) {
    __shared__ int buf[2][MAXB];
    int t = threadIdx.x;            // 512 threads
    int v = (t < nb) ? bcnt[t] : 0;
    buf[0][t] = v;
    __syncthreads();
    int cur = 0;
#pragma unroll
    for (int off = 1; off < MAXB; off <<= 1) {
        int nv = buf[cur][t] + (t >= off ? buf[cur][t - off] : 0);
        buf[cur ^ 1][t] = nv;
        __syncthreads();
        cur ^= 1;
    }
    int excl = buf[cur][t] - v;
    if (t < nb) { bstart[t] = excl; bcursor[t] = excl; }
    if (t == nb - 1) bstart[nb] = excl + v;
}

// bucket scatter using precomputed per-block counts (hall): one pass over edges.
__global__ __launch_bounds__(1024) void k_bscatter(const int* __restrict__ src,
                                                   const int* __restrict__ dst,
                                                   const int* __restrict__ hall,
                                                   int* __restrict__ bcursor,
                                                   uint32_t* __restrict__ bedges,
                                                   int e, int chunk, int nb) {
    __shared__ int hbase[MAXB];
    __shared__ int hpos[MAXB];
    int t = threadIdx.x, b = blockIdx.x;
    for (int i = t; i < nb; i += 1024) {
        int c = hall[(size_t)b * MAXB + i];
        hpos[i] = 0;
        hbase[i] = c ? atomicAdd(&bcursor[i], c) : 0;
    }
    __syncthreads();
    int e0 = b * chunk, e1 = min(e0 + chunk, e);
    for (int i = e0 + t; i < e1; i += 1024) {
        int d = dst[i];
        int bb = d >> TSH;
        int lp = atomicAdd(&hpos[bb], 1);
        bedges[hbase[bb] + lp] = ((uint32_t)(d & (TILE - 1)) << 18) | (uint32_t)src[i];
    }
}

// per-bucket counting sort, key = local_dst*2 + (src >= half):
// csr segments come out dst-ordered with each node's entries partitioned by
// src-half. Emits node_start[d], node_mid[d], dis[d].
__global__ __launch_bounds__(1024) void k_sort(const uint32_t* __restrict__ bedges,
                                               const int* __restrict__ bstart,
                                               uint32_t* __restrict__ csr,
                                               int* __restrict__ node_start,
                                               int* __restrict__ node_mid,
                                               float* __restrict__ dis,
                                               int n, int half) {
    __shared__ int hist[TILE * 2];
    __shared__ int sb[2][TILE * 2];
    __shared__ int curp[TILE * 2];
    int t = threadIdx.x;            // 1024 threads
    int b = blockIdx.x;
    int s0 = bstart[b], s1 = bstart[b + 1];

    hist[t] = 0;                    // TILE*2 == 1024
    __syncthreads();
    for (int i = s0 + t; i < s1; i += 1024) {
        uint32_t p = bedges[i];
        int key = ((int)(p >> 18) << 1) | ((int)(p & 0x3FFFFu) >= half ? 1 : 0);
        atomicAdd(&hist[key], 1);
    }
    __syncthreads();

    sb[0][t] = hist[t];
    __syncthreads();
    int cur = 0;
#pragma unroll
    for (int off = 1; off < TILE * 2; off <<= 1) {
        int nv = sb[cur][t] + (t >= off ? sb[cur][t - off] : 0);
        sb[cur ^ 1][t] = nv;
        __syncthreads();
        cur ^= 1;
    }
    int ex = sb[cur][t] - hist[t];          // exclusive
    curp[t] = ex;
    __syncthreads();
    if (t < TILE) {
        int d = (b << TSH) + t;
        if (d <= n) node_start[d] = s0 + curp[2 * t];
        if (d < n) {
            node_mid[d] = s0 + curp[2 * t + 1];
            dis[d] = rsqrtf((float)(hist[2 * t] + hist[2 * t + 1]) + 1.0f);
        }
    }
    __syncthreads();

    for (int i = s0 + t; i < s1; i += 1024) {
        uint32_t p = bedges[i];
        int key = ((int)(p >> 18) << 1) | ((int)(p & 0x3FFFFu) >= half ? 1 : 0);
        int pos = atomicAdd(&curp[key], 1);
        csr[s0 + pos] = p & 0x3FFFFu;
    }
}

// h1q = int8( h1 * dis[row] * 127/rowmax ), scl[row] = rowmax/127, via MFMA.
__global__ __launch_bounds__(TPB) void k_gemm_mfma(const float* __restrict__ x,
                                                   const float* __restrict__ W1,
                                                   const float* __restrict__ dis,
                                                   int8_t* __restrict__ h1q,
                                                   float* __restrict__ scl, int n) {
    int l   = threadIdx.x & 63;
    int wid = threadIdx.x >> 6;      // wave 0..3
    int lg  = l >> 4;                // 0..3
    int ln  = l & 15;

    f16x8 bf[4][2];
#pragma unroll
    for (int s = 0; s < 4; ++s)
#pragma unroll
        for (int t = 0; t < 2; ++t)
#pragma unroll
            for (int e = 0; e < 8; ++e)
                bf[s][t][e] = (_Float16)W1[(32 * s + 8 * lg + e) * 32 + 16 * t + ln];

    int ntiles = (n + 15) >> 4;
    int stride = gridDim.x * 4;
    for (int tile = blockIdx.x * 4 + wid; tile < ntiles; tile += stride) {
        int row = (tile << 4) + ln;
        bool rv = row < n;
        const float* xr = x + (size_t)row * 128 + 8 * lg;

        f32x4 acc0 = {0.f, 0.f, 0.f, 0.f};
        f32x4 acc1 = {0.f, 0.f, 0.f, 0.f};
#pragma unroll
        for (int s = 0; s < 4; ++s) {
            float4 lo, hi;
            if (rv) {
                lo = *(const float4*)(xr + 32 * s);
                hi = *(const float4*)(xr + 32 * s + 4);
            } else {
                lo = make_float4(0.f, 0.f, 0.f, 0.f);
                hi = lo;
            }
            f16x8 a;
            a[0] = (_Float16)lo.x; a[1] = (_Float16)lo.y;
            a[2] = (_Float16)lo.z; a[3] = (_Float16)lo.w;
            a[4] = (_Float16)hi.x; a[5] = (_Float16)hi.y;
            a[6] = (_Float16)hi.z; a[7] = (_Float16)hi.w;
            acc0 = __builtin_amdgcn_mfma_f32_16x16x32_f16(a, bf[s][0], acc0, 0, 0, 0);
            acc1 = __builtin_amdgcn_mfma_f32_16x16x32_f16(a, bf[s][1], acc1, 0, 0, 0);
        }

        int trow = tile << 4;
#pragma unroll
        for (int i = 0; i < 4; ++i) {
            int rowc = trow + 4 * lg + i;    // uniform across the 16-lane group
            if (rowc < n) {
                float dd = dis[rowc];
                float v0 = acc0[i] * dd;
                float v1 = acc1[i] * dd;
                float m = fmaxf(fabsf(v0), fabsf(v1));
                m = fmaxf(m, __shfl_xor(m, 1));
                m = fmaxf(m, __shfl_xor(m, 2));
                m = fmaxf(m, __shfl_xor(m, 4));
                m = fmaxf(m, __shfl_xor(m, 8));
                m = fmaxf(m, 1e-20f);
                float qs = 127.0f / m;
                h1q[(size_t)rowc * 32 + ln]      = (int8_t)(int)rintf(v0 * qs);
                h1q[(size_t)rowc * 32 + 16 + ln] = (int8_t)(int)rintf(v1 * qs);
                if (ln == 0) scl[rowc] = m * (1.0f / 127.0f);
            }
        }
    }
}

// Gather pass A (src < half): partial sum over [node_start, node_mid) -> accA fp16.
__global__ __launch_bounds__(TPB) void k_gpassA(const int* __restrict__ node_start,
                                                const int* __restrict__ node_mid,
                                                const uint32_t* __restrict__ csr,
                                                const int8_t* __restrict__ h1q,
                                                const float* __restrict__ scl,
                                                __half* __restrict__ accA, int n) {
    int t = blockIdx.x * TPB + threadIdx.x;
    int d = t >> 5, c = t & 31;
    if (d >= n) return;

    int e  = node_start[d];
    int e1 = node_mid[d];

    float acc = 0.0f;
    for (; e + 7 < e1; e += 8) {
        uint32_t s[8];
#pragma unroll
        for (int u = 0; u < 8; ++u)
            s[u] = __builtin_nontemporal_load(&csr[e + u]);
#pragma unroll
        for (int u = 0; u < 8; ++u)
            acc = fmaf((float)(int)h1q[(size_t)s[u] * 32 + c], scl[s[u]], acc);
    }
    for (; e < e1; ++e) {
        uint32_t s = __builtin_nontemporal_load(&csr[e]);
        acc = fmaf((float)(int)h1q[(size_t)s * 32 + c], scl[s], acc);
    }
    accA[(size_t)d * 32 + c] = __float2half(acc);
}

// Gather pass B (src >= half) + accA + fused self/bias/relu/dropout/W2 -> hw2.
__global__ __launch_bounds__(TPB) void k_gpassB(const int* __restrict__ node_start,
                                                const int* __restrict__ node_mid,
                                                const uint32_t* __restrict__ csr,
                                                const int8_t* __restrict__ h1q,
                                                const float* __restrict__ scl,
                                                const __half* __restrict__ accA,
                                                const float* __restrict__ dis,
                                                const float* __restrict__ b1,
                                                const float* __restrict__ drop_u,
                                                const float* __restrict__ W2,
                                                float* __restrict__ hw2, int n) {
    int t = blockIdx.x * TPB + threadIdx.x;
    int d = t >> 5, c = t & 31;
    if (d >= n) return;

    int e  = node_mid[d];
    int e1 = node_start[d + 1];

    float acc = 0.0f;
    for (; e + 7 < e1; e += 8) {
        uint32_t s[8];
#pragma unroll
        for (int u = 0; u < 8; ++u)
            s[u] = __builtin_nontemporal_load(&csr[e + u]);
#pragma unroll
        for (int u = 0; u < 8; ++u)
            acc = fmaf((float)(int)h1q[(size_t)s[u] * 32 + c], scl[s[u]], acc);
    }
    for (; e < e1; ++e) {
        uint32_t s = __builtin_nontemporal_load(&csr[e]);
        acc = fmaf((float)(int)h1q[(size_t)s * 32 + c], scl[s], acc);
    }
    acc += __half2float(accA[(size_t)d * 32 + c]);

    float dd = dis[d];
    float selfv = (float)(int)h1q[(size_t)d * 32 + c] * scl[d];
    float v = dd * (acc + selfv) + b1[c];
    v = fmaxf(v, 0.0f);
    float du = __builtin_nontemporal_load(&drop_u[(size_t)d * 32 + c]);
    v = (du > 0.5f) ? v * 2.0f : 0.0f;

    float p0 = v * W2[c * 2 + 0];
    float p1 = v * W2[c * 2 + 1];
#pragma unroll
    for (int off = 16; off >= 1; off >>= 1) {
        p0 += __shfl_xor(p0, off, 32);
        p1 += __shfl_xor(p1, off, 32);
    }
    if (c == 0) {
        float2 o; o.x = p0 * dd; o.y = p1 * dd;
        ((float2*)hw2)[d] = o;
    }
}

// Layer2 gather: out[d] = dis[d]*(sum_s hw2[s] + hw2[d]) + b2
__global__ __launch_bounds__(TPB) void k_gather2(const int* __restrict__ node_start,
                                                 const uint32_t* __restrict__ csr,
                                                 const float* __restrict__ dis,
                                                 const float* __restrict__ hw2,
                                                 const float* __restrict__ b2,
                                                 float* __restrict__ out, int n) {
    int t = blockIdx.x * TPB + threadIdx.x;
    int d = t >> 5, lane = t & 31;
    if (d >= n) return;

    int e0 = node_start[d];
    int e1 = node_start[d + 1];

    float a0 = 0.0f, a1 = 0.0f;
    for (int e = e0 + lane; e < e1; e += 32) {
        uint32_t s = __builtin_nontemporal_load(&csr[e]);
        float2 hv = ((const float2*)hw2)[s];
        a0 += hv.x;
        a1 += hv.y;
    }
#pragma unroll
    for (int off = 16; off >= 1; off >>= 1) {
        a0 += __shfl_xor(a0, off, 32);
        a1 += __shfl_xor(a1, off, 32);
    }
    if (lane == 0) {
        float dd = dis[d];
        float2 hv = ((const float2*)hw2)[d];
        out[(size_t)d * 2 + 0] = dd * (a0 + hv.x) + b2[0];
        out[(size_t)d * 2 + 1] = dd * (a1 + hv.y) + b2[1];
    }
}

extern "C" void kernel_launch(void* const* d_in, const int* in_sizes, int n_in,
                              void* d_out, int out_size, void* d_ws, size_t ws_size,
                              hipStream_t stream) {
    const float* x     = (const float*)d_in[0];
    const int*   ei    = (const int*)d_in[1];
    const float* W1    = (const float*)d_in[2];
    const float* b1    = (const float*)d_in[3];
    const float* W2    = (const float*)d_in[4];
    const float* b2    = (const float*)d_in[5];
    const float* dropu = (const float*)d_in[6];
    float* out = (float*)d_out;

    const int N = in_sizes[0] / 128;
    const int E = in_sizes[1] / 2;
    const int* src = ei;
    const int* dst = ei + E;

    const int NB = (N + TILE - 1) >> TSH;     // 391 for N=200000
    const int HALF = N / 2;

    // ws: dis f32[N] | scl f32[N] | hw2 f32[2N] | node_start i32[N+1] |
    //     node_mid i32[N] | bcnt i32[MAXB] | bstart i32[MAXB+1] | bcursor i32[MAXB]
    //     | hall i32[MAXB*MAXB] | bedges u32[E] | csr u32[E] | h1q i8[32N] |
    //     accA f16[32N]
    float* dis = (float*)d_ws;
    float* scl = dis + N;
    float* hw2 = scl + N;
    int* node_start = (int*)(hw2 + (size_t)N * 2);
    int* node_mid   = node_start + (N + 1);
    int* bcnt    = node_mid + N;
    int* bstart  = bcnt + MAXB;
    int* bcursor = bstart + (MAXB + 1);
    int* hall    = bcursor + MAXB;
    uint32_t* bedges = (uint32_t*)(hall + (size_t)MAXB * MAXB);
    uint32_t* csr    = bedges + E;
    int8_t* h1q = (int8_t*)(csr + E);
    __half* accA = (__half*)(h1q + (size_t)N * 32);

    const int chunk = (E + NB - 1) / NB;
    const int gG = (N * 32 + TPB - 1) / TPB;  // 32 lanes per node
    const int ntiles = (N + 15) >> 4;
    const int gT = (ntiles + 3) / 4;          // 4 waves (tiles) per block

    k_zero_i   <<<(MAXB + TPB - 1) / TPB, TPB, 0, stream>>>(bcnt, MAXB);
    k_bhist    <<<NB, 1024, 0, stream>>>(dst, bcnt, hall, E, chunk, NB);
    k_bscan    <<<1, MAXB, 0, stream>>>(bcnt, bstart, bcursor, NB);
    k_bscatter <<<NB, 1024, 0, stream>>>(src, dst, hall, bcursor, bedges, E, chunk, NB);
    k_sort     <<<NB, 1024, 0, stream>>>(bedges, bstart, csr, node_start, node_mid, dis, N, HALF);
    k_gemm_mfma<<<gT, TPB, 0, stream>>>(x, W1, dis, h1q, scl, N);
    k_gpassA   <<<gG, TPB, 0, stream>>>(node_start, node_mid, csr, h1q, scl, accA, N);
    k_gpassB   <<<gG, TPB, 0, stream>>>(node_start, node_mid, csr, h1q, scl, accA,
                                        dis, b1, dropu, W2, hw2, N);
    k_gather2  <<<gG, TPB, 0, stream>>>(node_start, csr, dis, hw2, b2, out, N);
}

// Round 15
// 370.340 us; speedup vs baseline: 1.1604x; 1.1604x over previous
//
#include <hip/hip_runtime.h>
#include <hip/hip_fp16.h>
#include <stdint.h>

// GCN 2-layer forward: two-level counting sort -> dst-sorted CSR -> pull gathers.
// h1w fp16 (dis-folded). GEMM via MFMA. gather1: csr loaded as 16B broadcast
// batches (2 per 8 edges, after alignment peel) -> ~1.25 VMEM instr/edge and
// row loads made independent (address-dependency once per 8 edges).

#define TPB 256
#define TILE 512           // nodes per bucket
#define TSH  9
#define MAXB 512           // supports N <= 262144 (src must fit 18 bits)

typedef _Float16 f16x8 __attribute__((ext_vector_type(8)));
typedef float    f32x4 __attribute__((ext_vector_type(4)));
typedef unsigned int u32x4 __attribute__((ext_vector_type(4)));

__global__ void k_zero_i(int* __restrict__ p, int m) {
    int i = blockIdx.x * TPB + threadIdx.x;
    if (i < m) p[i] = 0;
}

// chunked per-bucket histogram; spills per-block counts to hall and sums bcnt.
__global__ __launch_bounds__(1024) void k_bhist(const int* __restrict__ dst,
                                                int* __restrict__ bcnt,
                                                int* __restrict__ hall,
                                                int e, int chunk, int nb) {
    __shared__ int h[MAXB];
    int t = threadIdx.x, b = blockIdx.x;
    for (int i = t; i < MAXB; i += 1024) h[i] = 0;
    __syncthreads();
    int e0 = b * chunk, e1 = min(e0 + chunk, e);
    for (int i = e0 + t; i < e1; i += 1024)
        atomicAdd(&h[dst[i] >> TSH], 1);
    __syncthreads();
    for (int i = t; i < nb; i += 1024) {
        int c = h[i];
        hall[(size_t)b * MAXB + i] = c;
        if (c) atomicAdd(&bcnt[i], c);
    }
}

// single-block exclusive scan of bucket counts -> bstart, init bcursor
__global__ void k_bscan(const int* __restrict__ bcnt, int* __restrict__ bstart,
                        int* __restrict__ bcursor, int nb) {
    __shared__ int buf[2][MAXB];
    int t = threadIdx.x;            // 512 threads
    int v = (t < nb) ? bcnt[t] : 0;
    buf[0][t] = v;
    __syncthreads();
    int cur = 0;
#pragma unroll
    for (int off = 1; off < MAXB; off <<= 1) {
        int nv = buf[cur][t] + (t >= off ? buf[cur][t - off] : 0);
        buf[cur ^ 1][t] = nv;
        __syncthreads();
        cur ^= 1;
    }
    int excl = buf[cur][t] - v;
    if (t < nb) { bstart[t] = excl; bcursor[t] = excl; }
    if (t == nb - 1) bstart[nb] = excl + v;
}

// bucket scatter using precomputed per-block counts (hall): one pass over edges.
__global__ __launch_bounds__(1024) void k_bscatter(const int* __restrict__ src,
                                                   const int* __restrict__ dst,
                                                   const int* __restrict__ hall,
                                                   int* __restrict__ bcursor,
                                                   uint32_t* __restrict__ bedges,
                                                   int e, int chunk, int nb) {
    __shared__ int hbase[MAXB];
    __shared__ int hpos[MAXB];
    int t = threadIdx.x, b = blockIdx.x;
    for (int i = t; i < nb; i += 1024) {
        int c = hall[(size_t)b * MAXB + i];
        hpos[i] = 0;
        hbase[i] = c ? atomicAdd(&bcursor[i], c) : 0;
    }
    __syncthreads();
    int e0 = b * chunk, e1 = min(e0 + chunk, e);
    for (int i = e0 + t; i < e1; i += 1024) {
        int d = dst[i];
        int bb = d >> TSH;
        int lp = atomicAdd(&hpos[bb], 1);
        bedges[hbase[bb] + lp] = ((uint32_t)(d & (TILE - 1)) << 18) | (uint32_t)src[i];
    }
}

// per-bucket counting sort: bedges segment -> csr (src only, exact dst order).
// Also emits node_start[d] and dis[d].
__global__ __launch_bounds__(1024) void k_sort(const uint32_t* __restrict__ bedges,
                                               const int* __restrict__ bstart,
                                               uint32_t* __restrict__ csr,
                                               int* __restrict__ node_start,
                                               float* __restrict__ dis, int n) {
    __shared__ int hist[TILE];
    __shared__ int sb[2][TILE];
    __shared__ int curp[TILE];
    int t = threadIdx.x;            // 1024 threads
    int b = blockIdx.x;
    int s0 = bstart[b], s1 = bstart[b + 1];

    if (t < TILE) hist[t] = 0;
    __syncthreads();
    for (int i = s0 + t; i < s1; i += 1024)
        atomicAdd(&hist[bedges[i] >> 18], 1);
    __syncthreads();

    if (t < TILE) sb[0][t] = hist[t];
    __syncthreads();
    int cur = 0;
#pragma unroll
    for (int off = 1; off < TILE; off <<= 1) {
        if (t < TILE) {
            int nv = sb[cur][t] + (t >= off ? sb[cur][t - off] : 0);
            sb[cur ^ 1][t] = nv;
        }
        __syncthreads();
        cur ^= 1;
    }
    if (t < TILE) {
        int ex = sb[cur][t] - hist[t];          // exclusive
        curp[t] = ex;
        int d = (b << TSH) + t;
        if (d <= n) node_start[d] = s0 + ex;
        if (d < n)  dis[d] = rsqrtf((float)hist[t] + 1.0f);
    }
    __syncthreads();

    for (int i = s0 + t; i < s1; i += 1024) {
        uint32_t p = bedges[i];
        int ld = (int)(p >> 18);
        int pos = atomicAdd(&curp[ld], 1);
        csr[s0 + pos] = p & 0x3FFFFu;
    }
}

// h1w = fp16( (x @ W1) * dis[row] ) via MFMA (mfma_f32_16x16x32_f16).
__global__ __launch_bounds__(TPB) void k_gemm_mfma(const float* __restrict__ x,
                                                   const float* __restrict__ W1,
                                                   const float* __restrict__ dis,
                                                   __half* __restrict__ h1w, int n) {
    int l   = threadIdx.x & 63;
    int wid = threadIdx.x >> 6;      // wave 0..3
    int lg  = l >> 4;                // 0..3
    int ln  = l & 15;

    // preload B fragments (64 halves = 32 VGPR)
    f16x8 bf[4][2];
#pragma unroll
    for (int s = 0; s < 4; ++s)
#pragma unroll
        for (int t = 0; t < 2; ++t)
#pragma unroll
            for (int e = 0; e < 8; ++e)
                bf[s][t][e] = (_Float16)W1[(32 * s + 8 * lg + e) * 32 + 16 * t + ln];

    int ntiles = (n + 15) >> 4;
    int stride = gridDim.x * 4;
    for (int tile = blockIdx.x * 4 + wid; tile < ntiles; tile += stride) {
        int row = (tile << 4) + ln;          // A-row this lane supplies
        bool rv = row < n;
        const float* xr = x + (size_t)row * 128 + 8 * lg;

        f32x4 acc0 = {0.f, 0.f, 0.f, 0.f};
        f32x4 acc1 = {0.f, 0.f, 0.f, 0.f};
#pragma unroll
        for (int s = 0; s < 4; ++s) {
            float4 lo, hi;
            if (rv) {
                lo = *(const float4*)(xr + 32 * s);
                hi = *(const float4*)(xr + 32 * s + 4);
            } else {
                lo = make_float4(0.f, 0.f, 0.f, 0.f);
                hi = lo;
            }
            f16x8 a;
            a[0] = (_Float16)lo.x; a[1] = (_Float16)lo.y;
            a[2] = (_Float16)lo.z; a[3] = (_Float16)lo.w;
            a[4] = (_Float16)hi.x; a[5] = (_Float16)hi.y;
            a[6] = (_Float16)hi.z; a[7] = (_Float16)hi.w;
            acc0 = __builtin_amdgcn_mfma_f32_16x16x32_f16(a, bf[s][0], acc0, 0, 0, 0);
            acc1 = __builtin_amdgcn_mfma_f32_16x16x32_f16(a, bf[s][1], acc1, 0, 0, 0);
        }

        int trow = tile << 4;
#pragma unroll
        for (int i = 0; i < 4; ++i) {
            int rowc = trow + 4 * lg + i;
            if (rowc < n) {
                float dd = dis[rowc];
                h1w[(size_t)rowc * 32 + ln]      = __float2half(acc0[i] * dd);
                h1w[(size_t)rowc * 32 + 16 + ln] = __float2half(acc1[i] * dd);
            }
        }
    }
}

// Layer1 gather (fp16 rows) + fused self/bias/relu/dropout/W2 -> hw2.
// csr loaded as 16B broadcast batches after an alignment peel; the 8 row
// loads per batch are address-independent (MLP 8-deep per batch).
__global__ __launch_bounds__(TPB) void k_gather1(const int* __restrict__ node_start,
                                                 const uint32_t* __restrict__ csr,
                                                 const float* __restrict__ dis,
                                                 const __half* __restrict__ h1w,
                                                 const float* __restrict__ b1,
                                                 const float* __restrict__ drop_u,
                                                 const float* __restrict__ W2,
                                                 float* __restrict__ hw2, int n) {
    int t = blockIdx.x * TPB + threadIdx.x;
    int d = t >> 5, c = t & 31;
    if (d >= n) return;

    int e  = node_start[d];
    int e1 = node_start[d + 1];

    float acc = 0.0f;
    // peel to 16B-aligned csr index
    while (e < e1 && (e & 3)) {
        uint32_t s = __builtin_nontemporal_load(&csr[e]);
        acc += __half2float(h1w[(size_t)s * 32 + c]);
        ++e;
    }
    for (; e + 7 < e1; e += 8) {
        u32x4 ca = __builtin_nontemporal_load((const u32x4*)&csr[e]);
        u32x4 cb = __builtin_nontemporal_load((const u32x4*)&csr[e + 4]);
        float v0 = __half2float(h1w[(size_t)ca.x * 32 + c]);
        float v1 = __half2float(h1w[(size_t)ca.y * 32 + c]);
        float v2 = __half2float(h1w[(size_t)ca.z * 32 + c]);
        float v3 = __half2float(h1w[(size_t)ca.w * 32 + c]);
        float v4 = __half2float(h1w[(size_t)cb.x * 32 + c]);
        float v5 = __half2float(h1w[(size_t)cb.y * 32 + c]);
        float v6 = __half2float(h1w[(size_t)cb.z * 32 + c]);
        float v7 = __half2float(h1w[(size_t)cb.w * 32 + c]);
        acc += ((v0 + v1) + (v2 + v3)) + ((v4 + v5) + (v6 + v7));
    }
    if (e + 3 < e1) {
        u32x4 ca = __builtin_nontemporal_load((const u32x4*)&csr[e]);
        acc += (__half2float(h1w[(size_t)ca.x * 32 + c]) +
                __half2float(h1w[(size_t)ca.y * 32 + c])) +
               (__half2float(h1w[(size_t)ca.z * 32 + c]) +
                __half2float(h1w[(size_t)ca.w * 32 + c]));
        e += 4;
    }
    for (; e < e1; ++e) {
        uint32_t s = __builtin_nontemporal_load(&csr[e]);
        acc += __half2float(h1w[(size_t)s * 32 + c]);
    }

    float dd = dis[d];
    float selfv = __half2float(h1w[(size_t)d * 32 + c]);
    float v = dd * (acc + selfv) + b1[c];
    v = fmaxf(v, 0.0f);
    float du = __builtin_nontemporal_load(&drop_u[(size_t)d * 32 + c]);
    v = (du > 0.5f) ? v * 2.0f : 0.0f;

    float p0 = v * W2[c * 2 + 0];
    float p1 = v * W2[c * 2 + 1];
#pragma unroll
    for (int off = 16; off >= 1; off >>= 1) {
        p0 += __shfl_xor(p0, off, 32);
        p1 += __shfl_xor(p1, off, 32);
    }
    if (c == 0) {
        float2 o; o.x = p0 * dd; o.y = p1 * dd;
        ((float2*)hw2)[d] = o;
    }
}

// Layer2 gather: out[d] = dis[d]*(sum_s hw2[s] + hw2[d]) + b2
__global__ __launch_bounds__(TPB) void k_gather2(const int* __restrict__ node_start,
                                                 const uint32_t* __restrict__ csr,
                                                 const float* __restrict__ dis,
                                                 const float* __restrict__ hw2,
                                                 const float* __restrict__ b2,
                                                 float* __restrict__ out, int n) {
    int t = blockIdx.x * TPB + threadIdx.x;
    int d = t >> 5, lane = t & 31;
    if (d >= n) return;

    int e0 = node_start[d];
    int e1 = node_start[d + 1];

    float a0 = 0.0f, a1 = 0.0f;
    for (int e = e0 + lane; e < e1; e += 32) {
        uint32_t s = __builtin_nontemporal_load(&csr[e]);
        float2 hv = ((const float2*)hw2)[s];
        a0 += hv.x;
        a1 += hv.y;
    }
#pragma unroll
    for (int off = 16; off >= 1; off >>= 1) {
        a0 += __shfl_xor(a0, off, 32);
        a1 += __shfl_xor(a1, off, 32);
    }
    if (lane == 0) {
        float dd = dis[d];
        float2 hv = ((const float2*)hw2)[d];
        out[(size_t)d * 2 + 0] = dd * (a0 + hv.x) + b2[0];
        out[(size_t)d * 2 + 1] = dd * (a1 + hv.y) + b2[1];
    }
}

extern "C" void kernel_launch(void* const* d_in, const int* in_sizes, int n_in,
                              void* d_out, int out_size, void* d_ws, size_t ws_size,
                              hipStream_t stream) {
    const float* x     = (const float*)d_in[0];
    const int*   ei    = (const int*)d_in[1];
    const float* W1    = (const float*)d_in[2];
    const float* b1    = (const float*)d_in[3];
    const float* W2    = (const float*)d_in[4];
    const float* b2    = (const float*)d_in[5];
    const float* dropu = (const float*)d_in[6];
    float* out = (float*)d_out;

    const int N = in_sizes[0] / 128;
    const int E = in_sizes[1] / 2;
    const int* src = ei;
    const int* dst = ei + E;

    const int NB = (N + TILE - 1) >> TSH;     // 391 for N=200000

    // ws: dis f32[N] | hw2 f32[2N] | node_start i32[N+1] | bcnt i32[MAXB] |
    //     bstart i32[MAXB+1] | bcursor i32[MAXB] | hall i32[MAXB*MAXB] |
    //     bedges u32[E] | csr u32[E] | h1w fp16[32N]
    float* dis = (float*)d_ws;
    float* hw2 = dis + N;
    int* node_start = (int*)(hw2 + (size_t)N * 2);
    int* bcnt    = node_start + (N + 1);
    int* bstart  = bcnt + MAXB;
    int* bcursor = bstart + (MAXB + 1);
    int* hall    = bcursor + MAXB;
    uint32_t* bedges = (uint32_t*)(hall + (size_t)MAXB * MAXB);
    uint32_t* csr    = bedges + E;
    __half* h1w = (__half*)(csr + E);

    const int chunk = (E + NB - 1) / NB;
    const int gG = (N * 32 + TPB - 1) / TPB;  // 32 lanes per node
    const int ntiles = (N + 15) >> 4;
    const int gT = (ntiles + 3) / 4;          // 4 waves (tiles) per block

    k_zero_i   <<<(MAXB + TPB - 1) / TPB, TPB, 0, stream>>>(bcnt, MAXB);
    k_bhist    <<<NB, 1024, 0, stream>>>(dst, bcnt, hall, E, chunk, NB);
    k_bscan    <<<1, MAXB, 0, stream>>>(bcnt, bstart, bcursor, NB);
    k_bscatter <<<NB, 1024, 0, stream>>>(src, dst, hall, bcursor, bedges, E, chunk, NB);
    k_sort     <<<NB, 1024, 0, stream>>>(bedges, bstart, csr, node_start, dis, N);
    k_gemm_mfma<<<gT, TPB, 0, stream>>>(x, W1, dis, h1w, N);
    k_gather1  <<<gG, TPB, 0, stream>>>(node_start, csr, dis, h1w, b1, dropu, W2, hw2, N);
    k_gather2  <<<gG, TPB, 0, stream>>>(node_start, csr, dis, hw2, b2, out, N);
}

// Round 16
// 340.604 us; speedup vs baseline: 1.2617x; 1.0873x over previous
//
#include <hip/hip_runtime.h>
#include <hip/hip_fp16.h>
#include <stdint.h>

// GCN 2-layer forward: two-level counting sort -> dst-sorted CSR -> pull gathers.
// gather1 v2: 4 lanes per edge (lane = edge-slot*4 + row-quarter), one fp16x8
// load per lane -> 1 row-VMEM instruction per 16 edges per wave (8x fewer).
// GEMM via MFMA. h1w fp16 (dis-folded).

#define TPB 256
#define TILE 512           // nodes per bucket
#define TSH  9
#define MAXB 512           // supports N <= 262144 (src must fit 18 bits)

typedef _Float16 f16x8 __attribute__((ext_vector_type(8)));
typedef float    f32x4 __attribute__((ext_vector_type(4)));

__global__ void k_zero_i(int* __restrict__ p, int m) {
    int i = blockIdx.x * TPB + threadIdx.x;
    if (i < m) p[i] = 0;
}

// chunked per-bucket histogram; spills per-block counts to hall and sums bcnt.
__global__ __launch_bounds__(1024) void k_bhist(const int* __restrict__ dst,
                                                int* __restrict__ bcnt,
                                                int* __restrict__ hall,
                                                int e, int chunk, int nb) {
    __shared__ int h[MAXB];
    int t = threadIdx.x, b = blockIdx.x;
    for (int i = t; i < MAXB; i += 1024) h[i] = 0;
    __syncthreads();
    int e0 = b * chunk, e1 = min(e0 + chunk, e);
    for (int i = e0 + t; i < e1; i += 1024)
        atomicAdd(&h[dst[i] >> TSH], 1);
    __syncthreads();
    for (int i = t; i < nb; i += 1024) {
        int c = h[i];
        hall[(size_t)b * MAXB + i] = c;
        if (c) atomicAdd(&bcnt[i], c);
    }
}

// single-block exclusive scan of bucket counts -> bstart, init bcursor
__global__ void k_bscan(const int* __restrict__ bcnt, int* __restrict__ bstart,
                        int* __restrict__ bcursor, int nb) {
    __shared__ int buf[2][MAXB];
    int t = threadIdx.x;            // 512 threads
    int v = (t < nb) ? bcnt[t] : 0;
    buf[0][t] = v;
    __syncthreads();
    int cur = 0;
#pragma unroll
    for (int off = 1; off < MAXB; off <<= 1) {
        int nv = buf[cur][t] + (t >= off ? buf[cur][t - off] : 0);
        buf[cur ^ 1][t] = nv;
        __syncthreads();
        cur ^= 1;
    }
    int excl = buf[cur][t] - v;
    if (t < nb) { bstart[t] = excl; bcursor[t] = excl; }
    if (t == nb - 1) bstart[nb] = excl + v;
}

// bucket scatter using precomputed per-block counts (hall): one pass over edges.
__global__ __launch_bounds__(1024) void k_bscatter(const int* __restrict__ src,
                                                   const int* __restrict__ dst,
                                                   const int* __restrict__ hall,
                                                   int* __restrict__ bcursor,
                                                   uint32_t* __restrict__ bedges,
                                                   int e, int chunk, int nb) {
    __shared__ int hbase[MAXB];
    __shared__ int hpos[MAXB];
    int t = threadIdx.x, b = blockIdx.x;
    for (int i = t; i < nb; i += 1024) {
        int c = hall[(size_t)b * MAXB + i];
        hpos[i] = 0;
        hbase[i] = c ? atomicAdd(&bcursor[i], c) : 0;
    }
    __syncthreads();
    int e0 = b * chunk, e1 = min(e0 + chunk, e);
    for (int i = e0 + t; i < e1; i += 1024) {
        int d = dst[i];
        int bb = d >> TSH;
        int lp = atomicAdd(&hpos[bb], 1);
        bedges[hbase[bb] + lp] = ((uint32_t)(d & (TILE - 1)) << 18) | (uint32_t)src[i];
    }
}

// per-bucket counting sort: bedges segment -> csr (src only, exact dst order).
// Also emits node_start[d] and dis[d].
__global__ __launch_bounds__(1024) void k_sort(const uint32_t* __restrict__ bedges,
                                               const int* __restrict__ bstart,
                                               uint32_t* __restrict__ csr,
                                               int* __restrict__ node_start,
                                               float* __restrict__ dis, int n) {
    __shared__ int hist[TILE];
    __shared__ int sb[2][TILE];
    __shared__ int curp[TILE];
    int t = threadIdx.x;            // 1024 threads
    int b = blockIdx.x;
    int s0 = bstart[b], s1 = bstart[b + 1];

    if (t < TILE) hist[t] = 0;
    __syncthreads();
    for (int i = s0 + t; i < s1; i += 1024)
        atomicAdd(&hist[bedges[i] >> 18], 1);
    __syncthreads();

    if (t < TILE) sb[0][t] = hist[t];
    __syncthreads();
    int cur = 0;
#pragma unroll
    for (int off = 1; off < TILE; off <<= 1) {
        if (t < TILE) {
            int nv = sb[cur][t] + (t >= off ? sb[cur][t - off] : 0);
            sb[cur ^ 1][t] = nv;
        }
        __syncthreads();
        cur ^= 1;
    }
    if (t < TILE) {
        int ex = sb[cur][t] - hist[t];          // exclusive
        curp[t] = ex;
        int d = (b << TSH) + t;
        if (d <= n) node_start[d] = s0 + ex;
        if (d < n)  dis[d] = rsqrtf((float)hist[t] + 1.0f);
    }
    __syncthreads();

    for (int i = s0 + t; i < s1; i += 1024) {
        uint32_t p = bedges[i];
        int ld = (int)(p >> 18);
        int pos = atomicAdd(&curp[ld], 1);
        csr[s0 + pos] = p & 0x3FFFFu;
    }
}

// h1w = fp16( (x @ W1) * dis[row] ) via MFMA (mfma_f32_16x16x32_f16).
__global__ __launch_bounds__(TPB) void k_gemm_mfma(const float* __restrict__ x,
                                                   const float* __restrict__ W1,
                                                   const float* __restrict__ dis,
                                                   __half* __restrict__ h1w, int n) {
    int l   = threadIdx.x & 63;
    int wid = threadIdx.x >> 6;      // wave 0..3
    int lg  = l >> 4;                // 0..3
    int ln  = l & 15;

    // preload B fragments (64 halves = 32 VGPR)
    f16x8 bf[4][2];
#pragma unroll
    for (int s = 0; s < 4; ++s)
#pragma unroll
        for (int t = 0; t < 2; ++t)
#pragma unroll
            for (int e = 0; e < 8; ++e)
                bf[s][t][e] = (_Float16)W1[(32 * s + 8 * lg + e) * 32 + 16 * t + ln];

    int ntiles = (n + 15) >> 4;
    int stride = gridDim.x * 4;
    for (int tile = blockIdx.x * 4 + wid; tile < ntiles; tile += stride) {
        int row = (tile << 4) + ln;          // A-row this lane supplies
        bool rv = row < n;
        const float* xr = x + (size_t)row * 128 + 8 * lg;

        f32x4 acc0 = {0.f, 0.f, 0.f, 0.f};
        f32x4 acc1 = {0.f, 0.f, 0.f, 0.f};
#pragma unroll
        for (int s = 0; s < 4; ++s) {
            float4 lo, hi;
            if (rv) {
                lo = *(const float4*)(xr + 32 * s);
                hi = *(const float4*)(xr + 32 * s + 4);
            } else {
                lo = make_float4(0.f, 0.f, 0.f, 0.f);
                hi = lo;
            }
            f16x8 a;
            a[0] = (_Float16)lo.x; a[1] = (_Float16)lo.y;
            a[2] = (_Float16)lo.z; a[3] = (_Float16)lo.w;
            a[4] = (_Float16)hi.x; a[5] = (_Float16)hi.y;
            a[6] = (_Float16)hi.z; a[7] = (_Float16)hi.w;
            acc0 = __builtin_amdgcn_mfma_f32_16x16x32_f16(a, bf[s][0], acc0, 0, 0, 0);
            acc1 = __builtin_amdgcn_mfma_f32_16x16x32_f16(a, bf[s][1], acc1, 0, 0, 0);
        }

        int trow = tile << 4;
#pragma unroll
        for (int i = 0; i < 4; ++i) {
            int rowc = trow + 4 * lg + i;
            if (rowc < n) {
                float dd = dis[rowc];
                h1w[(size_t)rowc * 32 + ln]      = __float2half(acc0[i] * dd);
                h1w[(size_t)rowc * 32 + 16 + ln] = __float2half(acc1[i] * dd);
            }
        }
    }
}

// Layer1 gather v2: 32-lane group per dst node; lane = (slot<<2)|q.
// Per iteration the group covers 8 edges; each lane loads 16B (quarter row).
// One row-VMEM instruction per 16 edges per wave. Fused self/bias/relu/
// dropout/W2 epilogue computed per-quarter then q-reduced.
__global__ __launch_bounds__(TPB) void k_gather1(const int* __restrict__ node_start,
                                                 const uint32_t* __restrict__ csr,
                                                 const float* __restrict__ dis,
                                                 const __half* __restrict__ h1w,
                                                 const float* __restrict__ b1,
                                                 const float* __restrict__ drop_u,
                                                 const float* __restrict__ W2,
                                                 float* __restrict__ hw2, int n) {
    int t = blockIdx.x * TPB + threadIdx.x;
    int d = t >> 5, l = t & 31;
    if (d >= n) return;
    int slot = l >> 2;            // 0..7: edge slot
    int q    = l & 3;             // 0..3: row quarter
    int q8   = q * 8;

    int e0 = node_start[d];
    int e1 = node_start[d + 1];

    float acc[8];
#pragma unroll
    for (int j = 0; j < 8; ++j) acc[j] = 0.f;

    for (int eb = e0; eb < e1; eb += 8) {
        int ee = eb + slot;
        bool valid = ee < e1;
        uint32_t s = valid ? csr[ee] : (uint32_t)d;   // safe dummy row
        f16x8 r = *(const f16x8*)(h1w + (size_t)s * 32 + q8);
        if (valid) {
#pragma unroll
            for (int j = 0; j < 8; ++j) acc[j] += (float)r[j];
        }
    }

    // reduce across the 8 edge slots (lane bits 2..4)
#pragma unroll
    for (int off = 4; off <= 16; off <<= 1) {
#pragma unroll
        for (int j = 0; j < 8; ++j)
            acc[j] += __shfl_xor(acc[j], off, 32);
    }

    float dd = dis[d];
    f16x8 sf = *(const f16x8*)(h1w + (size_t)d * 32 + q8);
    f32x4 du0 = *(const f32x4*)(drop_u + (size_t)d * 32 + q8);
    f32x4 du1 = *(const f32x4*)(drop_u + (size_t)d * 32 + q8 + 4);

    float p0 = 0.f, p1 = 0.f;
#pragma unroll
    for (int j = 0; j < 8; ++j) {
        float v = dd * (acc[j] + (float)sf[j]) + b1[q8 + j];
        v = fmaxf(v, 0.f);
        float du = (j < 4) ? du0[j] : du1[j - 4];
        v = (du > 0.5f) ? v * 2.f : 0.f;
        p0 = fmaf(v, W2[(q8 + j) * 2 + 0], p0);
        p1 = fmaf(v, W2[(q8 + j) * 2 + 1], p1);
    }
    // combine the 4 quarters (lane bits 0..1)
    p0 += __shfl_xor(p0, 1, 32); p0 += __shfl_xor(p0, 2, 32);
    p1 += __shfl_xor(p1, 1, 32); p1 += __shfl_xor(p1, 2, 32);

    if (l == 0) {
        float2 o; o.x = p0 * dd; o.y = p1 * dd;
        ((float2*)hw2)[d] = o;
    }
}

// Layer2 gather: out[d] = dis[d]*(sum_s hw2[s] + hw2[d]) + b2
__global__ __launch_bounds__(TPB) void k_gather2(const int* __restrict__ node_start,
                                                 const uint32_t* __restrict__ csr,
                                                 const float* __restrict__ dis,
                                                 const float* __restrict__ hw2,
                                                 const float* __restrict__ b2,
                                                 float* __restrict__ out, int n) {
    int t = blockIdx.x * TPB + threadIdx.x;
    int d = t >> 5, lane = t & 31;
    if (d >= n) return;

    int e0 = node_start[d];
    int e1 = node_start[d + 1];

    float a0 = 0.0f, a1 = 0.0f;
    for (int e = e0 + lane; e < e1; e += 32) {
        int s = csr[e];
        float2 hv = ((const float2*)hw2)[s];
        a0 += hv.x;
        a1 += hv.y;
    }
#pragma unroll
    for (int off = 16; off >= 1; off >>= 1) {
        a0 += __shfl_xor(a0, off, 32);
        a1 += __shfl_xor(a1, off, 32);
    }
    if (lane == 0) {
        float dd = dis[d];
        float2 hv = ((const float2*)hw2)[d];
        out[(size_t)d * 2 + 0] = dd * (a0 + hv.x) + b2[0];
        out[(size_t)d * 2 + 1] = dd * (a1 + hv.y) + b2[1];
    }
}

extern "C" void kernel_launch(void* const* d_in, const int* in_sizes, int n_in,
                              void* d_out, int out_size, void* d_ws, size_t ws_size,
                              hipStream_t stream) {
    const float* x     = (const float*)d_in[0];
    const int*   ei    = (const int*)d_in[1];
    const float* W1    = (const float*)d_in[2];
    const float* b1    = (const float*)d_in[3];
    const float* W2    = (const float*)d_in[4];
    const float* b2    = (const float*)d_in[5];
    const float* dropu = (const float*)d_in[6];
    float* out = (float*)d_out;

    const int N = in_sizes[0] / 128;
    const int E = in_sizes[1] / 2;
    const int* src = ei;
    const int* dst = ei + E;

    const int NB = (N + TILE - 1) >> TSH;     // 391 for N=200000

    // ws: dis f32[N] | hw2 f32[2N] | node_start i32[N+1] | bcnt i32[MAXB] |
    //     bstart i32[MAXB+1] | bcursor i32[MAXB] | hall i32[MAXB*MAXB] |
    //     bedges u32[E] | csr u32[E] | h1w fp16[32N]
    float* dis = (float*)d_ws;
    float* hw2 = dis + N;
    int* node_start = (int*)(hw2 + (size_t)N * 2);
    int* bcnt    = node_start + (N + 1);
    int* bstart  = bcnt + MAXB;
    int* bcursor = bstart + (MAXB + 1);
    int* hall    = bcursor + MAXB;
    uint32_t* bedges = (uint32_t*)(hall + (size_t)MAXB * MAXB);
    uint32_t* csr    = bedges + E;
    __half* h1w = (__half*)(csr + E);

    const int chunk = (E + NB - 1) / NB;
    const int gG = (N * 32 + TPB - 1) / TPB;  // 32 lanes per node
    const int ntiles = (N + 15) >> 4;
    const int gT = (ntiles + 3) / 4;          // 4 waves (tiles) per block

    k_zero_i   <<<(MAXB + TPB - 1) / TPB, TPB, 0, stream>>>(bcnt, MAXB);
    k_bhist    <<<NB, 1024, 0, stream>>>(dst, bcnt, hall, E, chunk, NB);
    k_bscan    <<<1, MAXB, 0, stream>>>(bcnt, bstart, bcursor, NB);
    k_bscatter <<<NB, 1024, 0, stream>>>(src, dst, hall, bcursor, bedges, E, chunk, NB);
    k_sort     <<<NB, 1024, 0, stream>>>(bedges, bstart, csr, node_start, dis, N);
    k_gemm_mfma<<<gT, TPB, 0, stream>>>(x, W1, dis, h1w, N);
    k_gather1  <<<gG, TPB, 0, stream>>>(node_start, csr, dis, h1w, b1, dropu, W2, hw2, N);
    k_gather2  <<<gG, TPB, 0, stream>>>(node_start, csr, dis, hw2, b2, out, N);
}

// Round 17
// 311.320 us; speedup vs baseline: 1.3804x; 1.0941x over previous
//
#include <hip/hip_runtime.h>
#include <hip/hip_fp16.h>
#include <stdint.h>

// GCN 2-layer forward: two-level counting sort -> dst-sorted CSR -> pull gathers.
// gather1 v3: int8 rows (32B, per-row scale), 2 lanes/edge x 16B -> 16 edges per
// row-VMEM instruction, scl = 1 extra VMEM per 16 edges. GEMM via MFMA with
// int8-quantize epilogue (verified round 12, absmax 9.77e-4).
// bhist/bscatter: int4-vectorized edge reads (chunk rounded to x4).

#define TPB 256
#define TILE 512           // nodes per bucket
#define TSH  9
#define MAXB 512           // supports N <= 262144 (src must fit 18 bits)

typedef _Float16 f16x8 __attribute__((ext_vector_type(8)));
typedef float    f32x4 __attribute__((ext_vector_type(4)));
typedef signed char i8x16 __attribute__((ext_vector_type(16)));

__global__ void k_zero_i(int* __restrict__ p, int m) {
    int i = blockIdx.x * TPB + threadIdx.x;
    if (i < m) p[i] = 0;
}

// chunked per-bucket histogram; spills per-block counts to hall and sums bcnt.
// dst read 4-wide where aligned.
__global__ __launch_bounds__(1024) void k_bhist(const int* __restrict__ dst,
                                                int* __restrict__ bcnt,
                                                int* __restrict__ hall,
                                                int e, int chunk, int nb) {
    __shared__ int h[MAXB];
    int t = threadIdx.x, b = blockIdx.x;
    for (int i = t; i < MAXB; i += 1024) h[i] = 0;
    __syncthreads();
    int e0 = b * chunk, e1 = min(e0 + chunk, e);
    int cnt = e1 - e0;
    if (cnt > 0) {
        if ((((uintptr_t)(dst + e0)) & 15) == 0) {
            int nq = cnt >> 2;
            for (int qi = t; qi < nq; qi += 1024) {
                int4 dv = *(const int4*)&dst[e0 + qi * 4];
                atomicAdd(&h[dv.x >> TSH], 1);
                atomicAdd(&h[dv.y >> TSH], 1);
                atomicAdd(&h[dv.z >> TSH], 1);
                atomicAdd(&h[dv.w >> TSH], 1);
            }
            for (int j = e0 + (nq << 2) + t; j < e1; j += 1024)
                atomicAdd(&h[dst[j] >> TSH], 1);
        } else {
            for (int j = e0 + t; j < e1; j += 1024)
                atomicAdd(&h[dst[j] >> TSH], 1);
        }
    }
    __syncthreads();
    for (int i = t; i < nb; i += 1024) {
        int c = h[i];
        hall[(size_t)b * MAXB + i] = c;
        if (c) atomicAdd(&bcnt[i], c);
    }
}

// single-block exclusive scan of bucket counts -> bstart, init bcursor
__global__ void k_bscan(const int* __restrict__ bcnt, int* __restrict__ bstart,
                        int* __restrict__ bcursor, int nb) {
    __shared__ int buf[2][MAXB];
    int t = threadIdx.x;            // 512 threads
    int v = (t < nb) ? bcnt[t] : 0;
    buf[0][t] = v;
    __syncthreads();
    int cur = 0;
#pragma unroll
    for (int off = 1; off < MAXB; off <<= 1) {
        int nv = buf[cur][t] + (t >= off ? buf[cur][t - off] : 0);
        buf[cur ^ 1][t] = nv;
        __syncthreads();
        cur ^= 1;
    }
    int excl = buf[cur][t] - v;
    if (t < nb) { bstart[t] = excl; bcursor[t] = excl; }
    if (t == nb - 1) bstart[nb] = excl + v;
}

// bucket scatter using precomputed per-block counts (hall); src/dst read 4-wide.
__global__ __launch_bounds__(1024) void k_bscatter(const int* __restrict__ src,
                                                   const int* __restrict__ dst,
                                                   const int* __restrict__ hall,
                                                   int* __restrict__ bcursor,
                                                   uint32_t* __restrict__ bedges,
                                                   int e, int chunk, int nb) {
    __shared__ int hbase[MAXB];
    __shared__ int hpos[MAXB];
    int t = threadIdx.x, b = blockIdx.x;
    for (int i = t; i < nb; i += 1024) {
        int c = hall[(size_t)b * MAXB + i];
        hpos[i] = 0;
        hbase[i] = c ? atomicAdd(&bcursor[i], c) : 0;
    }
    __syncthreads();
    int e0 = b * chunk, e1 = min(e0 + chunk, e);
    int cnt = e1 - e0;
    if (cnt <= 0) return;
    if (((((uintptr_t)(dst + e0)) | ((uintptr_t)(src + e0))) & 15) == 0) {
        int nq = cnt >> 2;
        for (int qi = t; qi < nq; qi += 1024) {
            int4 dv = *(const int4*)&dst[e0 + qi * 4];
            int4 sv = *(const int4*)&src[e0 + qi * 4];
            int dd[4] = {dv.x, dv.y, dv.z, dv.w};
            int ss[4] = {sv.x, sv.y, sv.z, sv.w};
#pragma unroll
            for (int u = 0; u < 4; ++u) {
                int bb = dd[u] >> TSH;
                int lp = atomicAdd(&hpos[bb], 1);
                bedges[hbase[bb] + lp] =
                    ((uint32_t)(dd[u] & (TILE - 1)) << 18) | (uint32_t)ss[u];
            }
        }
        for (int j = e0 + (nq << 2) + t; j < e1; j += 1024) {
            int d = dst[j];
            int bb = d >> TSH;
            int lp = atomicAdd(&hpos[bb], 1);
            bedges[hbase[bb] + lp] = ((uint32_t)(d & (TILE - 1)) << 18) | (uint32_t)src[j];
        }
    } else {
        for (int j = e0 + t; j < e1; j += 1024) {
            int d = dst[j];
            int bb = d >> TSH;
            int lp = atomicAdd(&hpos[bb], 1);
            bedges[hbase[bb] + lp] = ((uint32_t)(d & (TILE - 1)) << 18) | (uint32_t)src[j];
        }
    }
}

// per-bucket counting sort: bedges segment -> csr (src only, exact dst order).
// Also emits node_start[d] and dis[d].
__global__ __launch_bounds__(1024) void k_sort(const uint32_t* __restrict__ bedges,
                                               const int* __restrict__ bstart,
                                               uint32_t* __restrict__ csr,
                                               int* __restrict__ node_start,
                                               float* __restrict__ dis, int n) {
    __shared__ int hist[TILE];
    __shared__ int sb[2][TILE];
    __shared__ int curp[TILE];
    int t = threadIdx.x;            // 1024 threads
    int b = blockIdx.x;
    int s0 = bstart[b], s1 = bstart[b + 1];

    if (t < TILE) hist[t] = 0;
    __syncthreads();
    for (int i = s0 + t; i < s1; i += 1024)
        atomicAdd(&hist[bedges[i] >> 18], 1);
    __syncthreads();

    if (t < TILE) sb[0][t] = hist[t];
    __syncthreads();
    int cur = 0;
#pragma unroll
    for (int off = 1; off < TILE; off <<= 1) {
        if (t < TILE) {
            int nv = sb[cur][t] + (t >= off ? sb[cur][t - off] : 0);
            sb[cur ^ 1][t] = nv;
        }
        __syncthreads();
        cur ^= 1;
    }
    if (t < TILE) {
        int ex = sb[cur][t] - hist[t];          // exclusive
        curp[t] = ex;
        int d = (b << TSH) + t;
        if (d <= n) node_start[d] = s0 + ex;
        if (d < n)  dis[d] = rsqrtf((float)hist[t] + 1.0f);
    }
    __syncthreads();

    for (int i = s0 + t; i < s1; i += 1024) {
        uint32_t p = bedges[i];
        int ld = (int)(p >> 18);
        int pos = atomicAdd(&curp[ld], 1);
        csr[s0 + pos] = p & 0x3FFFFu;
    }
}

// h1q = int8( h1 * dis[row] * 127/rowmax ), scl[row] = rowmax/127, via MFMA.
__global__ __launch_bounds__(TPB) void k_gemm_mfma(const float* __restrict__ x,
                                                   const float* __restrict__ W1,
                                                   const float* __restrict__ dis,
                                                   int8_t* __restrict__ h1q,
                                                   float* __restrict__ scl, int n) {
    int l   = threadIdx.x & 63;
    int wid = threadIdx.x >> 6;      // wave 0..3
    int lg  = l >> 4;                // 0..3
    int ln  = l & 15;

    f16x8 bf[4][2];
#pragma unroll
    for (int s = 0; s < 4; ++s)
#pragma unroll
        for (int t = 0; t < 2; ++t)
#pragma unroll
            for (int e = 0; e < 8; ++e)
                bf[s][t][e] = (_Float16)W1[(32 * s + 8 * lg + e) * 32 + 16 * t + ln];

    int ntiles = (n + 15) >> 4;
    int stride = gridDim.x * 4;
    for (int tile = blockIdx.x * 4 + wid; tile < ntiles; tile += stride) {
        int row = (tile << 4) + ln;
        bool rv = row < n;
        const float* xr = x + (size_t)row * 128 + 8 * lg;

        f32x4 acc0 = {0.f, 0.f, 0.f, 0.f};
        f32x4 acc1 = {0.f, 0.f, 0.f, 0.f};
#pragma unroll
        for (int s = 0; s < 4; ++s) {
            float4 lo, hi;
            if (rv) {
                lo = *(const float4*)(xr + 32 * s);
                hi = *(const float4*)(xr + 32 * s + 4);
            } else {
                lo = make_float4(0.f, 0.f, 0.f, 0.f);
                hi = lo;
            }
            f16x8 a;
            a[0] = (_Float16)lo.x; a[1] = (_Float16)lo.y;
            a[2] = (_Float16)lo.z; a[3] = (_Float16)lo.w;
            a[4] = (_Float16)hi.x; a[5] = (_Float16)hi.y;
            a[6] = (_Float16)hi.z; a[7] = (_Float16)hi.w;
            acc0 = __builtin_amdgcn_mfma_f32_16x16x32_f16(a, bf[s][0], acc0, 0, 0, 0);
            acc1 = __builtin_amdgcn_mfma_f32_16x16x32_f16(a, bf[s][1], acc1, 0, 0, 0);
        }

        int trow = tile << 4;
#pragma unroll
        for (int i = 0; i < 4; ++i) {
            int rowc = trow + 4 * lg + i;    // uniform across the 16-lane group
            if (rowc < n) {
                float dd = dis[rowc];
                float v0 = acc0[i] * dd;
                float v1 = acc1[i] * dd;
                float m = fmaxf(fabsf(v0), fabsf(v1));
                m = fmaxf(m, __shfl_xor(m, 1));
                m = fmaxf(m, __shfl_xor(m, 2));
                m = fmaxf(m, __shfl_xor(m, 4));
                m = fmaxf(m, __shfl_xor(m, 8));
                m = fmaxf(m, 1e-20f);
                float qs = 127.0f / m;
                h1q[(size_t)rowc * 32 + ln]      = (int8_t)(int)rintf(v0 * qs);
                h1q[(size_t)rowc * 32 + 16 + ln] = (int8_t)(int)rintf(v1 * qs);
                if (ln == 0) scl[rowc] = m * (1.0f / 127.0f);
            }
        }
    }
}

// Layer1 gather v3: 32-lane group per dst node; lane = slot*2 + q.
// Per iteration the group covers 16 edges; each lane loads 16B (half of a
// 32B int8 row) + the edge's scale. Fused self/bias/relu/dropout/W2 epilogue.
__global__ __launch_bounds__(TPB) void k_gather1(const int* __restrict__ node_start,
                                                 const uint32_t* __restrict__ csr,
                                                 const float* __restrict__ dis,
                                                 const int8_t* __restrict__ h1q,
                                                 const float* __restrict__ scl,
                                                 const float* __restrict__ b1,
                                                 const float* __restrict__ drop_u,
                                                 const float* __restrict__ W2,
                                                 float* __restrict__ hw2, int n) {
    int t = blockIdx.x * TPB + threadIdx.x;
    int d = t >> 5, l = t & 31;
    if (d >= n) return;
    int slot = l >> 1;            // 0..15: edge slot
    int q    = l & 1;             // 0..1: row half
    int q16  = q * 16;

    int e0 = node_start[d];
    int e1 = node_start[d + 1];

    float acc[16];
#pragma unroll
    for (int j = 0; j < 16; ++j) acc[j] = 0.f;

    for (int eb = e0; eb < e1; eb += 16) {
        int ee = eb + slot;
        bool valid = ee < e1;
        uint32_t s = valid ? csr[ee] : (uint32_t)d;   // safe dummy row
        i8x16 r = *(const i8x16*)(h1q + (size_t)s * 32 + q16);
        float sc = scl[s];
        if (!valid) sc = 0.f;
#pragma unroll
        for (int j = 0; j < 16; ++j)
            acc[j] = fmaf((float)r[j], sc, acc[j]);
    }

    // reduce across the 16 edge slots (lane bits 1..4)
#pragma unroll
    for (int off = 2; off <= 16; off <<= 1) {
#pragma unroll
        for (int j = 0; j < 16; ++j)
            acc[j] += __shfl_xor(acc[j], off, 32);
    }

    float dd = dis[d];
    i8x16 sf = *(const i8x16*)(h1q + (size_t)d * 32 + q16);
    float ssc = scl[d];
    f32x4 du0 = *(const f32x4*)(drop_u + (size_t)d * 32 + q16);
    f32x4 du1 = *(const f32x4*)(drop_u + (size_t)d * 32 + q16 + 4);
    f32x4 du2 = *(const f32x4*)(drop_u + (size_t)d * 32 + q16 + 8);
    f32x4 du3 = *(const f32x4*)(drop_u + (size_t)d * 32 + q16 + 12);

    float p0 = 0.f, p1 = 0.f;
#pragma unroll
    for (int j = 0; j < 16; ++j) {
        float v = dd * (acc[j] + (float)sf[j] * ssc) + b1[q16 + j];
        v = fmaxf(v, 0.f);
        float du = (j < 4) ? du0[j] : (j < 8) ? du1[j - 4] : (j < 12) ? du2[j - 8] : du3[j - 12];
        v = (du > 0.5f) ? v * 2.f : 0.f;
        p0 = fmaf(v, W2[(q16 + j) * 2 + 0], p0);
        p1 = fmaf(v, W2[(q16 + j) * 2 + 1], p1);
    }
    // combine the 2 halves (lane bit 0)
    p0 += __shfl_xor(p0, 1, 32);
    p1 += __shfl_xor(p1, 1, 32);

    if (l == 0) {
        float2 o; o.x = p0 * dd; o.y = p1 * dd;
        ((float2*)hw2)[d] = o;
    }
}

// Layer2 gather: out[d] = dis[d]*(sum_s hw2[s] + hw2[d]) + b2
__global__ __launch_bounds__(TPB) void k_gather2(const int* __restrict__ node_start,
                                                 const uint32_t* __restrict__ csr,
                                                 const float* __restrict__ dis,
                                                 const float* __restrict__ hw2,
                                                 const float* __restrict__ b2,
                                                 float* __restrict__ out, int n) {
    int t = blockIdx.x * TPB + threadIdx.x;
    int d = t >> 5, lane = t & 31;
    if (d >= n) return;

    int e0 = node_start[d];
    int e1 = node_start[d + 1];

    float a0 = 0.0f, a1 = 0.0f;
    for (int e = e0 + lane; e < e1; e += 32) {
        int s = csr[e];
        float2 hv = ((const float2*)hw2)[s];
        a0 += hv.x;
        a1 += hv.y;
    }
#pragma unroll
    for (int off = 16; off >= 1; off >>= 1) {
        a0 += __shfl_xor(a0, off, 32);
        a1 += __shfl_xor(a1, off, 32);
    }
    if (lane == 0) {
        float dd = dis[d];
        float2 hv = ((const float2*)hw2)[d];
        out[(size_t)d * 2 + 0] = dd * (a0 + hv.x) + b2[0];
        out[(size_t)d * 2 + 1] = dd * (a1 + hv.y) + b2[1];
    }
}

extern "C" void kernel_launch(void* const* d_in, const int* in_sizes, int n_in,
                              void* d_out, int out_size, void* d_ws, size_t ws_size,
                              hipStream_t stream) {
    const float* x     = (const float*)d_in[0];
    const int*   ei    = (const int*)d_in[1];
    const float* W1    = (const float*)d_in[2];
    const float* b1    = (const float*)d_in[3];
    const float* W2    = (const float*)d_in[4];
    const float* b2    = (const float*)d_in[5];
    const float* dropu = (const float*)d_in[6];
    float* out = (float*)d_out;

    const int N = in_sizes[0] / 128;
    const int E = in_sizes[1] / 2;
    const int* src = ei;
    const int* dst = ei + E;

    const int NB = (N + TILE - 1) >> TSH;     // 391 for N=200000

    // ws: dis f32[N] | scl f32[N] | hw2 f32[2N] | node_start i32[N+1] |
    //     bcnt i32[MAXB] | bstart i32[MAXB+1] | bcursor i32[MAXB] |
    //     hall i32[MAXB*MAXB] | bedges u32[E] | csr u32[E] | h1q i8[32N] (256-aligned)
    float* dis = (float*)d_ws;
    float* scl = dis + N;
    float* hw2 = scl + N;
    int* node_start = (int*)(hw2 + (size_t)N * 2);
    int* bcnt    = node_start + (N + 1);
    int* bstart  = bcnt + MAXB;
    int* bcursor = bstart + (MAXB + 1);
    int* hall    = bcursor + MAXB;
    uint32_t* bedges = (uint32_t*)(hall + (size_t)MAXB * MAXB);
    uint32_t* csr    = bedges + E;
    int8_t* h1q = (int8_t*)(((uintptr_t)(csr + E) + 255) & ~(uintptr_t)255);

    const int chunk = (((E + NB - 1) / NB) + 3) & ~3;   // multiple of 4
    const int gG = (N * 32 + TPB - 1) / TPB;  // 32 lanes per node
    const int ntiles = (N + 15) >> 4;
    const int gT = (ntiles + 3) / 4;          // 4 waves (tiles) per block

    k_zero_i   <<<(MAXB + TPB - 1) / TPB, TPB, 0, stream>>>(bcnt, MAXB);
    k_bhist    <<<NB, 1024, 0, stream>>>(dst, bcnt, hall, E, chunk, NB);
    k_bscan    <<<1, MAXB, 0, stream>>>(bcnt, bstart, bcursor, NB);
    k_bscatter <<<NB, 1024, 0, stream>>>(src, dst, hall, bcursor, bedges, E, chunk, NB);
    k_sort     <<<NB, 1024, 0, stream>>>(bedges, bstart, csr, node_start, dis, N);
    k_gemm_mfma<<<gT, TPB, 0, stream>>>(x, W1, dis, h1q, scl, N);
    k_gather1  <<<gG, TPB, 0, stream>>>(node_start, csr, dis, h1q, scl, b1, dropu, W2, hw2, N);
    k_gather2  <<<gG, TPB, 0, stream>>>(node_start, csr, dis, hw2, b2, out, N);
}